// Round 8
// baseline (159.074 us; speedup 1.0000x reference)
//
#include <hip/hip_runtime.h>

// (B,N,H,NB,NCT) = (8,4096,1024,128,33), H/2 = 512
#define NTOK 4096
#define HDIM 1024
#define HHALF 512
#define NBLK 128
#define CAP 256
#define XELEMS 33554432ull   // 8*4096*1024

typedef __attribute__((ext_vector_type(8))) short short8;
typedef __attribute__((ext_vector_type(4))) float f32x4;
typedef short bf16s;

__device__ __forceinline__ short f2bf(float f) {
    unsigned u = __builtin_bit_cast(unsigned, f);
    u = (u + 0x7fffu + ((u >> 16) & 1u)) >> 16;   // RNE
    return (short)u;
}
__device__ __forceinline__ void gload_lds16(const void* g, void* l) {
    __builtin_amdgcn_global_load_lds(
        (const __attribute__((address_space(1))) unsigned int*)g,
        (__attribute__((address_space(3))) unsigned int*)l, 16, 0, 0);
}
__device__ __forceinline__ float fast_tanh(float v) {
    float e = __expf(2.0f * v);
    return 1.0f - 2.0f / (e + 1.0f);
}

// ---------------------------------------------------------------------------
// x (f32) -> xb (bf16), grid-stride, vectorized. Memory-bound (roofline).
// ---------------------------------------------------------------------------
__global__ void k_xcvt(const float* __restrict__ in, bf16s* __restrict__ out) {
    for (size_t i = ((size_t)blockIdx.x * 256 + threadIdx.x) * 8; i < XELEMS;
         i += (size_t)gridDim.x * 256 * 8) {
        float4 a = *reinterpret_cast<const float4*>(&in[i]);
        float4 b = *reinterpret_cast<const float4*>(&in[i + 4]);
        short h[8] = {f2bf(a.x), f2bf(a.y), f2bf(a.z), f2bf(a.w),
                      f2bf(b.x), f2bf(b.y), f2bf(b.z), f2bf(b.w)};
        *reinterpret_cast<int4*>(&out[i]) = *reinterpret_cast<const int4*>(h);
    }
}

// ---------------------------------------------------------------------------
// Tiled transpose+convert for both weights in one launch.
// ---------------------------------------------------------------------------
__global__ void k_tcvt2(const float* __restrict__ W1, const float* __restrict__ Wp,
                        bf16s* __restrict__ w1t, bf16s* __restrict__ wpt) {
    __shared__ float tile[64][65];
    const int by = blockIdx.y;
    const float* in = (by < 8) ? W1 : Wp;
    bf16s* out = (by < 8) ? w1t : wpt;
    const int Nc = (by < 8) ? HHALF : HDIM;
    const int n0 = ((by < 8) ? by : (by - 8)) * 64;
    const int k0 = blockIdx.x * 64;
    const int tx = threadIdx.x & 63, ty = threadIdx.x >> 6;
    #pragma unroll
    for (int i = 0; i < 16; ++i) {
        int r = ty + i * 4;
        tile[r][tx] = in[(size_t)(k0 + r) * Nc + n0 + tx];
    }
    __syncthreads();
    #pragma unroll
    for (int i = 0; i < 16; ++i) {
        int r = ty + i * 4;
        out[(size_t)(n0 + r) * 1024 + k0 + tx] = f2bf(tile[tx][r]);
    }
}

// ---------------------------------------------------------------------------
// Gate GEMM: bf16 both operands via global_load_lds, TRI-buffered BK=32,
// counted-vmcnt schedule with 2-tile lookahead (vmcnt(8) waits for loads
// issued two compute phases ago). 128x128 tile, 4 waves (2x2), acc[4][4].
// LDS = 3*16KB = 48KB exactly (epilogue gp aliased into As) -> 3 wg/CU.
// Staging/fragment algebra identical to R5-proven BK=32 scheme.
// ---------------------------------------------------------------------------
__global__ __launch_bounds__(256, 3) void k_gemm_g(
    const bf16s* __restrict__ xb, const bf16s* __restrict__ w1t,
    const float* __restrict__ b1, const float* __restrict__ w2,
    float* __restrict__ partial)
{
    __shared__ alignas(16) bf16s As[3][128 * 32];   // 8KB each
    __shared__ alignas(16) bf16s Bs[3][128 * 32];   // total 48KB

    const int tid = threadIdx.x;
    const int lane = tid & 63;
    const int wv = tid >> 6;
    const int wr = wv >> 1, wc = wv & 1;
    const int phys = blockIdx.x;
    const int logical = (phys & 7) * 128 + (phys >> 3);   // 1024 = 8*128 bijective
    const int row0 = (logical >> 2) * 128;
    const int col0 = (logical & 3) * 128;
    const int c0 = lane & 15, khalf = lane >> 4;

    // staging: q in {0,1}: row r = wv*32 + q*16 + (lane>>2); chunk slot is
    // q-invariant since ((r+16)>>1)&3 == (r>>1)&3
    const int srow = wv * 32 + (lane >> 2);
    const int sj = (lane & 3) ^ ((srow >> 1) & 3);
    const bf16s* aSrc = &xb [(size_t)(row0 + srow) * HDIM + sj * 8];
    const bf16s* bSrc = &w1t[(size_t)(col0 + srow) * HDIM + sj * 8];
    const int sdst = (wv * 32) * 32 + lane * 8;     // + q*16*32 shorts

    f32x4 acc[4][4] = {};

    // prologue: tiles 0 and 1 (8 gll per wave in flight)
    #pragma unroll
    for (int q = 0; q < 2; ++q) {
        gload_lds16(aSrc + q * 16 * HDIM, &As[0][sdst + q * 512]);
        gload_lds16(bSrc + q * 16 * HDIM, &Bs[0][sdst + q * 512]);
    }
    #pragma unroll
    for (int q = 0; q < 2; ++q) {
        gload_lds16(aSrc + q * 16 * HDIM + 32, &As[1][sdst + q * 512]);
        gload_lds16(bSrc + q * 16 * HDIM + 32, &Bs[1][sdst + q * 512]);
    }

    for (int t = 0; t < 32; ++t) {
        const int cur = t % 3;
        if (t < 30) {
            const int nb = (t + 2) % 3;
            const int ko = (t + 2) * 32;
            #pragma unroll
            for (int q = 0; q < 2; ++q) {
                gload_lds16(aSrc + q * 16 * HDIM + ko, &As[nb][sdst + q * 512]);
                gload_lds16(bSrc + q * 16 * HDIM + ko, &Bs[nb][sdst + q * 512]);
            }
            asm volatile("s_waitcnt vmcnt(8)" ::: "memory");   // tile t done; t+1,t+2 in flight
        } else if (t == 30) {
            asm volatile("s_waitcnt vmcnt(4)" ::: "memory");   // tile 30 done; 31 in flight
        } else {
            asm volatile("s_waitcnt vmcnt(0)" ::: "memory");
        }
        __builtin_amdgcn_s_barrier();
        __builtin_amdgcn_sched_barrier(0);

        short8 av[4], bv[4];
        #pragma unroll
        for (int mf = 0; mf < 4; ++mf) {
            int ra = wr * 64 + mf * 16 + c0;
            av[mf] = *reinterpret_cast<const short8*>(
                &As[cur][ra * 32 + ((khalf ^ ((ra >> 1) & 3)) * 8)]);
        }
        #pragma unroll
        for (int nf = 0; nf < 4; ++nf) {
            int rb = wc * 64 + nf * 16 + c0;
            bv[nf] = *reinterpret_cast<const short8*>(
                &Bs[cur][rb * 32 + ((khalf ^ ((rb >> 1) & 3)) * 8)]);
        }

        __builtin_amdgcn_s_setprio(1);
        #pragma unroll
        for (int nf = 0; nf < 4; ++nf)
            #pragma unroll
            for (int mf = 0; mf < 4; ++mf)
                acc[mf][nf] = __builtin_amdgcn_mfma_f32_16x16x32_bf16(av[mf], bv[nf], acc[mf][nf], 0, 0, 0);
        __builtin_amdgcn_s_setprio(0);

        asm volatile("s_waitcnt lgkmcnt(0)" ::: "memory");
        __builtin_amdgcn_sched_barrier(0);
        __builtin_amdgcn_s_barrier();      // buf[cur] free for iter t+1's staging
    }

    // epilogue: per-row partial dot of tanh(h)*W2 over this wave's 64 cols.
    // gp aliased into As (all LDS reads drained by final lgkmcnt+barrier).
    float* gp = reinterpret_cast<float*>(&As[0][0]);   // [2][128]
    float b1v[4], w2v[4];
    #pragma unroll
    for (int nf = 0; nf < 4; ++nf) {
        int gc = col0 + wc * 64 + nf * 16 + c0;
        b1v[nf] = b1[gc];
        w2v[nf] = w2[gc];
    }
    #pragma unroll
    for (int mf = 0; mf < 4; ++mf) {
        #pragma unroll
        for (int reg = 0; reg < 4; ++reg) {
            float s = 0.f;
            #pragma unroll
            for (int nf = 0; nf < 4; ++nf)
                s += fast_tanh(acc[mf][nf][reg] + b1v[nf]) * w2v[nf];
            s += __shfl_xor(s, 1); s += __shfl_xor(s, 2);
            s += __shfl_xor(s, 4); s += __shfl_xor(s, 8);
            if (c0 == 0) gp[wc * 128 + wr * 64 + mf * 16 + khalf * 4 + reg] = s;
        }
    }
    __syncthreads();
    if (tid < 128)
        partial[(size_t)(logical & 3) * 32768 + row0 + tid] = gp[tid] + gp[128 + tid];
}

// ---------------------------------------------------------------------------
// Single-pass per-(b,block): sums the 4 gate partials for member tokens
// (writing gate[] once per valid token), online-softmax stats, ordered lists.
// ---------------------------------------------------------------------------
__global__ void k_blocks(const int* __restrict__ block_ids, const unsigned char* __restrict__ pad,
                         const float* __restrict__ part, const float* __restrict__ b2,
                         float* __restrict__ gate, const int* __restrict__ ct,
                         const float* __restrict__ ct_emb,
                         int* __restrict__ counts, float* __restrict__ mblk,
                         float* __restrict__ wscale, int* __restrict__ lists,
                         float* __restrict__ out_hasb)
{
    const int blk = blockIdx.x;
    const int b = blk >> 7, k = blk & 127;
    const int lane = threadIdx.x;
    const int base = b * NTOK;
    const int lbase = blk * CAP;
    const unsigned long long ltmask = (1ull << lane) - 1ull;
    const float b2v = b2[0];

    float m = -__builtin_inff();
    float s = 0.f;
    int pos = 0;
    for (int t0 = 0; t0 < NTOK; t0 += 64) {
        int t = t0 + lane;
        bool mt = (block_ids[base + t] == k) && (pad[base + t] == 0);
        unsigned long long mask = __ballot(mt);
        if (mt) {
            int r = base + t;
            float g = part[r] + part[32768 + r] + part[65536 + r] + part[98304 + r] + b2v;
            gate[r] = g;   // each valid token belongs to exactly one block
            int my = pos + __popcll(mask & ltmask);
            if (my < CAP) lists[lbase + my] = t;
            float mn = fmaxf(m, g);
            s = s * __expf(m - mn) + __expf(g - mn);
            m = mn;
        }
        pos += __popcll(mask);
    }
    #pragma unroll
    for (int off = 1; off < 64; off <<= 1) {
        float om = __shfl_xor(m, off);
        float os = __shfl_xor(s, off);
        float mn = fmaxf(m, om);
        float sa = (m == -__builtin_inff()) ? 0.f : s * __expf(m - mn);
        float sb = (om == -__builtin_inff()) ? 0.f : os * __expf(om - mn);
        s = sa + sb;
        m = mn;
    }
    if (lane == 0) {
        counts[blk] = pos;
        mblk[blk] = (pos > 0) ? m : 0.f;
        float mod = 1.0f + 0.1f * ct_emb[ct[b] * NBLK + k];
        wscale[blk] = (pos > 0 && s > 0.f) ? (mod / fmaxf(s, 1e-30f)) : 0.f;
        out_hasb[blk] = (pos > 0) ? 1.f : 0.f;
    }
}

// ---------------------------------------------------------------------------
// Pooling from bf16 xb: pooled[b,k,:] = wscale * sum_n exp(gate[n]-m) * xb[b,n,:]
// ---------------------------------------------------------------------------
__global__ void k_pool(const bf16s* __restrict__ xb, const float* __restrict__ gate,
                       const int* __restrict__ lists, const int* __restrict__ counts,
                       const float* __restrict__ mblk, const float* __restrict__ wscale,
                       bf16s* __restrict__ pooled)
{
    const int blk = blockIdx.x;
    const int b = blk >> 7;
    const int tid = threadIdx.x;
    const int base = b * NTOK;
    const int cnt = min(counts[blk], CAP);
    const int lbase = blk * CAP;
    const float m = mblk[blk], ws = wscale[blk];

    float4 acc = {0.f, 0.f, 0.f, 0.f};
    for (int i = 0; i < cnt; ++i) {
        int n = lists[lbase + i];
        float w = __expf(gate[base + n] - m);
        int2 rv = *reinterpret_cast<const int2*>(&xb[(size_t)(base + n) * HDIM + tid * 4]);
        short s4[4];
        *reinterpret_cast<int2*>(s4) = rv;
        unsigned u0 = ((unsigned)(unsigned short)s4[0]) << 16;
        unsigned u1 = ((unsigned)(unsigned short)s4[1]) << 16;
        unsigned u2 = ((unsigned)(unsigned short)s4[2]) << 16;
        unsigned u3 = ((unsigned)(unsigned short)s4[3]) << 16;
        acc.x += w * __builtin_bit_cast(float, u0);
        acc.y += w * __builtin_bit_cast(float, u1);
        acc.z += w * __builtin_bit_cast(float, u2);
        acc.w += w * __builtin_bit_cast(float, u3);
    }
    short o[4] = {f2bf(acc.x * ws), f2bf(acc.y * ws), f2bf(acc.z * ws), f2bf(acc.w * ws)};
    *reinterpret_cast<int2*>(&pooled[(size_t)blk * HDIM + tid * 4]) =
        *reinterpret_cast<const int2*>(o);
}

// ---------------------------------------------------------------------------
// GEMM2: y = pooled @ Wp + bp. 1024^3. 64x64 tiles, 4 waves, dbuf + gll,
// counted-vmcnt schedule (vmcnt(2) in-loop, raw barriers).
// ---------------------------------------------------------------------------
__global__ __launch_bounds__(256) void k_gemm2(
    const bf16s* __restrict__ pooled, const bf16s* __restrict__ wpt,
    const float* __restrict__ bp, float* __restrict__ y)
{
    __shared__ alignas(16) bf16s As[2][64 * 32];
    __shared__ alignas(16) bf16s Bs[2][64 * 32];
    const int tid = threadIdx.x;
    const int lane = tid & 63;
    const int wv = tid >> 6;
    const int wr = wv >> 1, wc = wv & 1;
    const int row0 = (blockIdx.x >> 4) * 64, col0 = (blockIdx.x & 15) * 64;
    const int c0 = lane & 15, khalf = lane >> 4;

    const int sr = wv * 16 + (lane >> 2);
    const int sj = (lane & 3) ^ ((sr >> 1) & 3);
    const int sdst = (wv * 16) * 32 + lane * 8;
    const bf16s* srcA = &pooled[(size_t)(row0 + sr) * 1024 + sj * 8];
    const bf16s* srcB = &wpt[(size_t)(col0 + sr) * 1024 + sj * 8];

    f32x4 acc[2][2] = {};

    gload_lds16(srcA, &As[0][sdst]);
    gload_lds16(srcB, &Bs[0][sdst]);

    for (int t = 0; t < 32; ++t) {
        const int cur = t & 1;
        if (t < 31) {
            gload_lds16(srcA + (t + 1) * 32, &As[cur ^ 1][sdst]);
            gload_lds16(srcB + (t + 1) * 32, &Bs[cur ^ 1][sdst]);
            asm volatile("s_waitcnt vmcnt(2)" ::: "memory");
        } else {
            asm volatile("s_waitcnt vmcnt(0)" ::: "memory");
        }
        __builtin_amdgcn_s_barrier();
        __builtin_amdgcn_sched_barrier(0);
        #pragma unroll
        for (int mf = 0; mf < 2; ++mf) {
            int ra = wr * 32 + mf * 16 + c0;
            short8 av = *reinterpret_cast<const short8*>(
                &As[cur][ra * 32 + ((khalf ^ ((ra >> 1) & 3)) * 8)]);
            #pragma unroll
            for (int nf = 0; nf < 2; ++nf) {
                int rb = wc * 32 + nf * 16 + c0;
                short8 bv = *reinterpret_cast<const short8*>(
                    &Bs[cur][rb * 32 + ((khalf ^ ((rb >> 1) & 3)) * 8)]);
                acc[mf][nf] = __builtin_amdgcn_mfma_f32_16x16x32_bf16(av, bv, acc[mf][nf], 0, 0, 0);
            }
        }
        asm volatile("s_waitcnt lgkmcnt(0)" ::: "memory");
        __builtin_amdgcn_sched_barrier(0);
        __builtin_amdgcn_s_barrier();
    }
    #pragma unroll
    for (int mf = 0; mf < 2; ++mf)
        #pragma unroll
        for (int nf = 0; nf < 2; ++nf)
            #pragma unroll
            for (int reg = 0; reg < 4; ++reg) {
                int grow = row0 + wr * 32 + mf * 16 + khalf * 4 + reg;
                int gcol = col0 + wc * 32 + nf * 16 + c0;
                y[(size_t)grow * 1024 + gcol] = acc[mf][nf][reg] + bp[gcol];
            }
}

// ---------------------------------------------------------------------------
// LayerNorm + ELU + present-mask.
// ---------------------------------------------------------------------------
__global__ void k_lnelu(const float* __restrict__ y, const float* __restrict__ ln_g,
                        const float* __restrict__ ln_b, const int* __restrict__ counts,
                        float* __restrict__ outp)
{
    const int row = blockIdx.x;
    const int k = row & 127;
    const int tid = threadIdx.x;

    float4 v = *reinterpret_cast<const float4*>(&y[(size_t)row * 1024 + tid * 4]);
    float s = v.x + v.y + v.z + v.w;
    float ss = v.x * v.x + v.y * v.y + v.z * v.z + v.w * v.w;
    #pragma unroll
    for (int off = 32; off; off >>= 1) { s += __shfl_xor(s, off); ss += __shfl_xor(ss, off); }

    __shared__ float sbuf[4], ssbuf[4];
    int wv = tid >> 6;
    if ((tid & 63) == 0) { sbuf[wv] = s; ssbuf[wv] = ss; }
    __syncthreads();
    s = sbuf[0] + sbuf[1] + sbuf[2] + sbuf[3];
    ss = ssbuf[0] + ssbuf[1] + ssbuf[2] + ssbuf[3];

    float mu = s * (1.f / 1024.f);
    float var = ss * (1.f / 1024.f) - mu * mu;
    float rstd = rsqrtf(var + 1e-5f);

    bool pres = false;
    #pragma unroll
    for (int bb = 0; bb < 8; ++bb) pres = pres || (counts[bb * NBLK + k] > 0);

    float4 g4 = *reinterpret_cast<const float4*>(&ln_g[tid * 4]);
    float4 b4 = *reinterpret_cast<const float4*>(&ln_b[tid * 4]);
    float vals[4] = {v.x, v.y, v.z, v.w};
    float gs[4] = {g4.x, g4.y, g4.z, g4.w};
    float bs[4] = {b4.x, b4.y, b4.z, b4.w};
    float4 o;
    float* op = &o.x;
    #pragma unroll
    for (int j = 0; j < 4; ++j) {
        float t = (vals[j] - mu) * rstd * gs[j] + bs[j];
        t = (t > 0.f) ? t : expm1f(t);
        op[j] = pres ? t : 0.f;
    }
    *reinterpret_cast<float4*>(&outp[(size_t)row * 1024 + tid * 4]) = o;
}

// ---------------------------------------------------------------------------
extern "C" void kernel_launch(void* const* d_in, const int* in_sizes, int n_in,
                              void* d_out, int out_size, void* d_ws, size_t ws_size,
                              hipStream_t stream)
{
    const float* x      = (const float*)d_in[0];
    const int*   ct     = (const int*)d_in[1];
    const int*   bids   = (const int*)d_in[2];
    const unsigned char* pad = (const unsigned char*)d_in[3];
    const float* W1     = (const float*)d_in[4];
    const float* b1     = (const float*)d_in[5];
    const float* W2     = (const float*)d_in[6];
    const float* b2     = (const float*)d_in[7];
    const float* ct_emb = (const float*)d_in[8];
    const float* Wp     = (const float*)d_in[9];
    const float* bp     = (const float*)d_in[10];
    const float* ln_g   = (const float*)d_in[11];
    const float* ln_b   = (const float*)d_in[12];
    float* outF = (float*)d_out;

    char* ws = (char*)d_ws;
    bf16s* w1t    = (bf16s*)(ws + 0);          //  1,048,576
    bf16s* wpt    = (bf16s*)(ws + 1048576);    //  2,097,152 -> 3,145,728
    float* gate   = (float*)(ws + 3145728);    //    131,072 -> 3,276,800
    float* part   = (float*)(ws + 3276800);    //    524,288 -> 3,801,088
    float* mblk   = (float*)(ws + 3801088);
    float* wscal  = (float*)(ws + 3805184);
    int*   counts = (int*)  (ws + 3809280);
    int*   lists  = (int*)  (ws + 3813376);    //  1,048,576 -> 4,861,952
    bf16s* pooled = (bf16s*)(ws + 4861952);    //  2,097,152 -> 6,959,104
    float* ybuf   = (float*)(ws + 6959104);    //  4,194,304 -> 11,153,408
    bf16s* xb     = (bf16s*)(ws + 11153408);   // 67,108,864 -> 78,262,272

    k_tcvt2<<<dim3(16, 24), 256, 0, stream>>>(W1, Wp, w1t, wpt);
    k_xcvt<<<2048, 256, 0, stream>>>(x, xb);
    k_gemm_g<<<1024, 256, 0, stream>>>(xb, w1t, b1, W2, part);
    k_blocks<<<1024, 64, 0, stream>>>(bids, pad, part, b2, gate, ct, ct_emb,
                                      counts, mblk, wscal, lists,
                                      outF + (size_t)8 * NBLK * HDIM);
    k_pool<<<1024, 256, 0, stream>>>(xb, gate, lists, counts, mblk, wscal, pooled);
    k_gemm2<<<256, 256, 0, stream>>>(pooled, wpt, bp, ybuf);
    k_lnelu<<<1024, 256, 0, stream>>>(ybuf, ln_g, ln_b, counts, outF);
}